// Round 4
// baseline (751.662 us; speedup 1.0000x reference)
//
#include <hip/hip_runtime.h>

#define N_NODES 50000
#define N_EDGES 800000
#define IN_C 256
#define HID_C 512
#define OUT_C 256
#define M_PAD 50048   // 391 * 128, covers 50000 with one padded tile
#define NPASS 8
#define PASS_SHIFT 13   // src >> 13 -> bucket 0..6 (8192-node source ranges)

typedef unsigned short u16;
typedef unsigned int   u32;
typedef u16  u16x4 __attribute__((ext_vector_type(4)));
typedef u16  u16x8 __attribute__((ext_vector_type(8)));
typedef short s16x8 __attribute__((ext_vector_type(8)));   // bf16 MFMA frag (guide §3)
typedef float f32x4 __attribute__((ext_vector_type(4)));

__device__ __forceinline__ float bf2f(u16 h) {
    u32 u = ((u32)h) << 16;
    return __builtin_bit_cast(float, u);
}
__device__ __forceinline__ u16 f2bf(float f) {   // round-to-nearest-even
    u32 u = __builtin_bit_cast(u32, f);
    u32 r = u + 0x7fffu + ((u >> 16) & 1u);
    return (u16)(r >> 16);
}
__device__ __forceinline__ void gload16(const void* g, void* l) {
    __builtin_amdgcn_global_load_lds(
        (const __attribute__((address_space(1))) u32*)g,
        (__attribute__((address_space(3))) u32*)l, 16, 0, 0);
}
__device__ __forceinline__ int swz4(int r) { return (r ^ (r >> 2)) & 3; }

// ---------------- sub-CSR build: buckets (dst, src>>13) ----------------
__global__ void k_hist8(const int* __restrict__ src, const int* __restrict__ dst,
                        int* __restrict__ cnt8) {
    int e = blockIdx.x * 256 + threadIdx.x;
    if (e < N_EDGES) {
        int q = src[e] >> PASS_SHIFT;
        atomicAdd(&cnt8[dst[e] * NPASS + q], 1);
    }
}

__global__ void k_partial(const int* __restrict__ cnt, int* __restrict__ bsum, int total) {
    __shared__ int s[256];
    int i = blockIdx.x * 256 + threadIdx.x;
    int v = (i < total) ? cnt[i] : 0;
    s[threadIdx.x] = v; __syncthreads();
    for (int o = 128; o > 0; o >>= 1) {
        if (threadIdx.x < o) s[threadIdx.x] += s[threadIdx.x + o];
        __syncthreads();
    }
    if (threadIdx.x == 0) bsum[blockIdx.x] = s[0];
}

// exclusive scan of nb block sums (nb may exceed 256): chunked Hillis-Steele + carry
__global__ void k_scanb(int* __restrict__ bsum, int nb) {
    __shared__ int s[256];
    int carry = 0;
    for (int base = 0; base < nb; base += 256) {
        int i = base + threadIdx.x;
        int v = (i < nb) ? bsum[i] : 0;
        s[threadIdx.x] = v; __syncthreads();
        for (int o = 1; o < 256; o <<= 1) {
            int t = (threadIdx.x >= o) ? s[threadIdx.x - o] : 0;
            __syncthreads();
            s[threadIdx.x] += t;
            __syncthreads();
        }
        int tot = s[255];
        if (i < nb) bsum[i] = s[threadIdx.x] - v + carry;
        carry += tot;
        __syncthreads();
    }
}

__global__ void k_rowptr8(const int* __restrict__ cnt, const int* __restrict__ bsum,
                          int* __restrict__ rp, int* __restrict__ cur, int total) {
    __shared__ int s[256];
    int i = blockIdx.x * 256 + threadIdx.x;
    int v = (i < total) ? cnt[i] : 0;
    s[threadIdx.x] = v; __syncthreads();
    for (int o = 1; o < 256; o <<= 1) {                     // Hillis-Steele inclusive
        int t = (threadIdx.x >= o) ? s[threadIdx.x - o] : 0;
        __syncthreads();
        s[threadIdx.x] += t;
        __syncthreads();
    }
    int excl = s[threadIdx.x] - v + bsum[blockIdx.x];
    if (i < total) { rp[i] = excl; cur[i] = excl; }
    if (i == total - 1) rp[total] = excl + v;
}

__global__ void k_scatter8(const int* __restrict__ src, const int* __restrict__ dst,
                           int* __restrict__ cur, int* __restrict__ col) {
    int e = blockIdx.x * 256 + threadIdx.x;
    if (e < N_EDGES) {
        int sv = src[e];
        int q = sv >> PASS_SHIFT;
        int p = atomicAdd(&cur[dst[e] * NPASS + q], 1);
        col[p] = sv;
    }
}

// -------------- weight prep: W[K][N] fp32 -> Wt[N][K] bf16 --------------
__global__ void k_wt(const float* __restrict__ w, u16* __restrict__ wt, int K, int N) {
    int idx = blockIdx.x * 256 + threadIdx.x;
    if (idx >= K * N) return;
    int n = idx / K, k = idx - n * K;
    wt[idx] = f2bf(w[(size_t)k * N + n]);
}

// -------------- x fp32 -> bf16 (halves gather bytes in agg_l1) --------------
__global__ void k_x2bf(const float* __restrict__ x, u16* __restrict__ xb) {
    int i = blockIdx.x * 256 + threadIdx.x;
    if (i < N_NODES * IN_C / 4) {
        float4 v = ((const float4*)x)[i];
        u16x4 o;
        o[0] = f2bf(v.x); o[1] = f2bf(v.y); o[2] = f2bf(v.z); o[3] = f2bf(v.w);
        ((u16x4*)xb)[i] = o;
    }
}

// ---- slab x source-range-pass aggregation (XCD-L2-resident gather) ----
// 128-B slabs (64 bf16 ch): C=512 -> 8 slabs, slab==bid&7 -> one slab per XCD,
// every line pulled by exactly one XCD; C=256 -> 4 slabs, 2 XCDs/slab.
// 8 source-range passes (outer loop, rp8 sub-CSR): per-XCD per-pass gather
// footprint = 8192 nodes x 128 B = 1 MB <= 4 MiB L2 -> gathers become L2 hits.
// Block: 256 thr = 16 groups x 16 lanes; group owns 8 nodes (k), lane owns 4 ch.
// Accumulators a[8][4] fp32 persist across passes (statically indexed).
// EPI 0: out bf16 = bf16(ep*self + agg).  EPI 1: out fp32 = ep*self + agg + bias.
template <int C, int EPI>
__global__ __launch_bounds__(256) void k_agg_pass(
    const u16* __restrict__ sm, const int* __restrict__ rp8,
    const int* __restrict__ col, const float* __restrict__ eps,
    const float* __restrict__ bias, void* __restrict__ out) {
    constexpr int NSLAB = C / 64;          // 128-B slabs
    const int j = blockIdx.x & 7;
    int slab, chunk;
    if constexpr (NSLAB == 8) { slab = j; chunk = blockIdx.x >> 3; }
    else { slab = j & 3; chunk = ((blockIdx.x >> 3) << 1) + (j >> 2); }
    const int gid = threadIdx.x >> 4;      // 16 groups of 16 lanes
    const int ln  = threadIdx.x & 15;
    const int ch0 = slab * 64 + ln * 4;
    const int nbase = chunk * 128;
    const float ep = 1.f + eps[0];

    float a[8][4];
#pragma unroll
    for (int k = 0; k < 8; k++) { a[k][0] = a[k][1] = a[k][2] = a[k][3] = 0.f; }

#pragma unroll 1
    for (int p = 0; p < NPASS; p++) {
#pragma unroll
        for (int k = 0; k < 8; k++) {
            int n = nbase + k * 16 + gid;
            if (n >= N_NODES) continue;
            int rs = rp8[n * NPASS + p], re = rp8[n * NPASS + p + 1];
            int e = rs;
            for (; e + 2 <= re; e += 2) {
                int s0 = col[e], s1 = col[e + 1];
                u16x4 v0 = *(const u16x4*)(sm + (size_t)s0 * C + ch0);
                u16x4 v1 = *(const u16x4*)(sm + (size_t)s1 * C + ch0);
#pragma unroll
                for (int q = 0; q < 4; q++) a[k][q] += bf2f(v0[q]) + bf2f(v1[q]);
            }
            if (e < re) {
                int s0 = col[e];
                u16x4 v0 = *(const u16x4*)(sm + (size_t)s0 * C + ch0);
#pragma unroll
                for (int q = 0; q < 4; q++) a[k][q] += bf2f(v0[q]);
            }
        }
    }

#pragma unroll
    for (int k = 0; k < 8; k++) {
        int n = nbase + k * 16 + gid;
        if (n >= N_NODES) continue;
        u16x4 sv = *(const u16x4*)(sm + (size_t)n * C + ch0);
        float r0 = fmaf(ep, bf2f(sv[0]), a[k][0]);
        float r1 = fmaf(ep, bf2f(sv[1]), a[k][1]);
        float r2 = fmaf(ep, bf2f(sv[2]), a[k][2]);
        float r3 = fmaf(ep, bf2f(sv[3]), a[k][3]);
        if constexpr (EPI == 0) {
            u16x4 o;
            o[0] = f2bf(r0); o[1] = f2bf(r1); o[2] = f2bf(r2); o[3] = f2bf(r3);
            *(u16x4*)((u16*)out + (size_t)n * C + ch0) = o;
        } else {
            float4 bv = *(const float4*)(bias + ch0);
            float4 o;
            o.x = r0 + bv.x; o.y = r1 + bv.y; o.z = r2 + bv.z; o.w = r3 + bv.w;
            *(float4*)((float*)out + (size_t)n * C + ch0) = o;
        }
    }
}

// -------------- bf16 MFMA GEMM: C[M][N] = A[M][K] @ Wt[N][K]^T --------------
// 128x128 tile, BK=32, 4 waves (2x2), global_load_lds staging with both-sides
// XOR chunk swizzle (rule 21): LDS tile [128 rows][32 bf16], row=64B=4 chunks,
// chunk c' = c ^ swz4(row) gives 2-way (free) bank access on ds_read_b128.
// EPI=0: out bf16 = relu(acc + bias).  EPI=1: out bf16 = acc (no bias/relu).
template <int K, int EPI>
__global__ __launch_bounds__(256, 2) void gemm_k(
    const u16* __restrict__ A, const u16* __restrict__ Wt,
    const float* __restrict__ bias, void* __restrict__ out,
    int N, int grid_n) {
    __shared__ u16 Als[128 * 32];
    __shared__ u16 Bls[128 * 32];
    const int tid  = threadIdx.x;
    const int wave = tid >> 6, lane = tid & 63;
    const int wm = wave >> 1, wn = wave & 1;
    const int bm = blockIdx.x / grid_n, bn = blockIdx.x % grid_n;
    const int m0 = bm * 128, n0 = bn * 128;
    const int sr = lane >> 2, sc = lane & 3;       // staging: 16 rows x 4 chunks
    const int fr = lane & 15, kg = lane >> 4;      // fragment coords

    f32x4 acc[4][4];
#pragma unroll
    for (int i = 0; i < 4; i++)
#pragma unroll
        for (int j = 0; j < 4; j++) acc[i][j] = (f32x4){0.f, 0.f, 0.f, 0.f};

    for (int kk = 0; kk < K; kk += 32) {
#pragma unroll
        for (int i = 0; i < 2; i++) {
            int rl = wave * 32 + i * 16 + sr;
            int c  = sc ^ swz4(rl);                 // pre-swizzled global source
            gload16(A  + (size_t)(m0 + rl) * K + kk + c * 8,
                    &Als[(wave * 32 + i * 16) * 32]);
            gload16(Wt + (size_t)(n0 + rl) * K + kk + c * 8,
                    &Bls[(wave * 32 + i * 16) * 32]);
        }
        asm volatile("s_waitcnt vmcnt(0)" ::: "memory");
        __syncthreads();

        s16x8 af[4], bfr[4];
#pragma unroll
        for (int mi = 0; mi < 4; mi++) {
            int r = wm * 64 + mi * 16 + fr;
            int c = kg ^ swz4(r);                   // swizzled read
            af[mi] = *(const s16x8*)&Als[r * 32 + c * 8];
        }
#pragma unroll
        for (int ni = 0; ni < 4; ni++) {
            int r = wn * 64 + ni * 16 + fr;
            int c = kg ^ swz4(r);
            bfr[ni] = *(const s16x8*)&Bls[r * 32 + c * 8];
        }
#pragma unroll
        for (int mi = 0; mi < 4; mi++)
#pragma unroll
            for (int ni = 0; ni < 4; ni++)
                acc[mi][ni] = __builtin_amdgcn_mfma_f32_16x16x32_bf16(
                    af[mi], bfr[ni], acc[mi][ni], 0, 0, 0);
        __syncthreads();
    }

    // epilogue: C row = kg*4 + j, col = fr (m89/m91-verified C/D layout)
#pragma unroll
    for (int ni = 0; ni < 4; ni++) {
        int cn = n0 + wn * 64 + ni * 16 + fr;
        float bv = 0.f;
        if constexpr (EPI == 0) bv = bias[cn];
#pragma unroll
        for (int mi = 0; mi < 4; mi++) {
            int rb = m0 + wm * 64 + mi * 16 + kg * 4;
#pragma unroll
            for (int j = 0; j < 4; j++) {
                int r = rb + j;
                if (r < N_NODES) {
                    float v = acc[mi][ni][j];
                    if constexpr (EPI == 0) {
                        v += bv;
                        v = v > 0.f ? v : 0.f;
                    }
                    ((u16*)out)[(size_t)r * N + cn] = f2bf(v);
                }
            }
        }
    }
}

// ---------------- launch ----------------
extern "C" void kernel_launch(void* const* d_in, const int* in_sizes, int n_in,
                              void* d_out, int out_size, void* d_ws, size_t ws_size,
                              hipStream_t stream) {
    const float* x    = (const float*)d_in[0];
    const int*   src  = (const int*)d_in[1];
    const int*   dst  = (const int*)d_in[2];
    const float* w1   = (const float*)d_in[3];
    const float* b1   = (const float*)d_in[4];
    const float* eps1 = (const float*)d_in[5];
    const float* w2   = (const float*)d_in[6];
    const float* b2   = (const float*)d_in[7];
    const float* eps2 = (const float*)d_in[8];
    const float* w3   = (const float*)d_in[9];
    const float* b3   = (const float*)d_in[10];
    const float* eps3 = (const float*)d_in[11];

    char* ws = (char*)d_ws;
    size_t off = 0;
    auto take = [&](size_t bytes) {
        char* p = ws + off;
        off += (bytes + 255) & ~(size_t)255;
        return p;
    };
    const int TOT8 = N_NODES * NPASS;                 // 400000 buckets
    int* cnt8 = (int*)take((size_t)TOT8 * 4);
    int* rp8  = (int*)take((size_t)(TOT8 + 1) * 4);
    int* cur8 = (int*)take((size_t)TOT8 * 4);
    int* bsum = (int*)take(2048 * 4);
    int* col  = (int*)take((size_t)N_EDGES * 4);
    u16* w1t  = (u16*)take((size_t)IN_C * HID_C * 2);
    u16* w2t  = (u16*)take((size_t)HID_C * HID_C * 2);
    u16* w3t  = (u16*)take((size_t)HID_C * OUT_C * 2);
    u16* A0   = (u16*)take((size_t)M_PAD * IN_C * 2);
    u16* h1   = (u16*)take((size_t)M_PAD * HID_C * 2);
    u16* A1   = (u16*)take((size_t)M_PAD * HID_C * 2);
    // time-shared buffer: xb (phase 1) -> A1 (phase 2) -> g3 bf16 (phase 3).
    // each is fully dead before the next is written; stream order serializes.
    u16* xb = A1;            // 25.6 MB <= 51.2 MB, dead after k_agg l1
    u16* h2 = h1;            // GEMM2 reads only A1 -> safe alias
    u16* g3 = A1;            // GEMM3 reads only h2 -> safe alias

    const int NB8 = (TOT8 + 255) / 256;   // 1563 scan blocks
    const int NE  = (N_EDGES + 255) / 256;

    hipMemsetAsync(cnt8, 0, (size_t)TOT8 * 4, stream);
    k_hist8  <<<NE, 256, 0, stream>>>(src, dst, cnt8);
    k_partial<<<NB8, 256, 0, stream>>>(cnt8, bsum, TOT8);
    k_scanb  <<<1, 256, 0, stream>>>(bsum, NB8);
    k_rowptr8<<<NB8, 256, 0, stream>>>(cnt8, bsum, rp8, cur8, TOT8);
    k_scatter8<<<NE, 256, 0, stream>>>(src, dst, cur8, col);

    k_wt<<<(IN_C * HID_C + 255) / 256, 256, 0, stream>>>(w1, w1t, IN_C, HID_C);
    k_wt<<<(HID_C * HID_C + 255) / 256, 256, 0, stream>>>(w2, w2t, HID_C, HID_C);
    k_wt<<<(HID_C * OUT_C + 255) / 256, 256, 0, stream>>>(w3, w3t, HID_C, OUT_C);
    k_x2bf<<<(N_NODES * IN_C / 4 + 255) / 256, 256, 0, stream>>>(x, xb);

    // grids: C=512 -> 391 chunks x 8 slabs; C=256 -> 196x8 (chunk pairs x 4 slabs)
    const int G512 = 391 * 8;
    const int G256 = 196 * 8;

    // layer 1: aggregate (256ch bf16) then GEMM -> h1 = relu(A0 @ W1 + b1)
    k_agg_pass<IN_C, 0><<<G256, 256, 0, stream>>>(xb, rp8, col, eps1, nullptr, A0);
    gemm_k<IN_C, 0><<<391 * (HID_C / 128), 256, 0, stream>>>(
        A0, w1t, b1, h1, HID_C, HID_C / 128);

    // layer 2: aggregate (512ch) then GEMM -> h2 = relu(A1 @ W2 + b2)
    k_agg_pass<HID_C, 0><<<G512, 256, 0, stream>>>(h1, rp8, col, eps2, nullptr, A1);
    gemm_k<HID_C, 0><<<391 * (HID_C / 128), 256, 0, stream>>>(
        A1, w2t, b2, h2, HID_C, HID_C / 128);

    // layer 3: GEMM first (g3 = h2 @ W3 bf16, no bias), then aggregate + bias -> fp32
    gemm_k<HID_C, 1><<<391 * (OUT_C / 128), 256, 0, stream>>>(
        h2, w3t, nullptr, g3, OUT_C, OUT_C / 128);
    k_agg_pass<OUT_C, 1><<<G256, 256, 0, stream>>>(g3, rp8, col, eps3, b3, (float*)d_out);
}

// Round 5
// 478.569 us; speedup vs baseline: 1.5706x; 1.5706x over previous
//
#include <hip/hip_runtime.h>

#define N_NODES 50000
#define N_EDGES 800000
#define IN_C 256
#define HID_C 512
#define OUT_C 256
#define M_PAD 50048   // 391 * 128, covers 50000 with one padded tile
#define NPASS 8
#define PASS_SHIFT 13   // src >> 13 -> bucket 0..6 (8192-node source ranges)

typedef unsigned short u16;
typedef unsigned int   u32;
typedef u16  u16x4 __attribute__((ext_vector_type(4)));
typedef u16  u16x8 __attribute__((ext_vector_type(8)));
typedef short s16x8 __attribute__((ext_vector_type(8)));   // bf16 MFMA frag (guide §3)
typedef float f32x4 __attribute__((ext_vector_type(4)));

__device__ __forceinline__ float bf2f(u16 h) {
    u32 u = ((u32)h) << 16;
    return __builtin_bit_cast(float, u);
}
__device__ __forceinline__ u16 f2bf(float f) {   // round-to-nearest-even
    u32 u = __builtin_bit_cast(u32, f);
    u32 r = u + 0x7fffu + ((u >> 16) & 1u);
    return (u16)(r >> 16);
}
__device__ __forceinline__ void gload16(const void* g, void* l) {
    __builtin_amdgcn_global_load_lds(
        (const __attribute__((address_space(1))) u32*)g,
        (__attribute__((address_space(3))) u32*)l, 16, 0, 0);
}
__device__ __forceinline__ int swz4(int r) { return (r ^ (r >> 2)) & 3; }

// ---------------- sub-CSR build: buckets (dst, src>>13) ----------------
// col ends up sorted by (dst, src>>13): per node the edge list is contiguous
// [rp8[n*8], rp8[n*8+8]) AND pass-sorted (source-window-ascending).
__global__ void k_hist8(const int* __restrict__ src, const int* __restrict__ dst,
                        int* __restrict__ cnt8) {
    int e = blockIdx.x * 256 + threadIdx.x;
    if (e < N_EDGES) {
        int q = src[e] >> PASS_SHIFT;
        atomicAdd(&cnt8[dst[e] * NPASS + q], 1);
    }
}

__global__ void k_partial(const int* __restrict__ cnt, int* __restrict__ bsum, int total) {
    __shared__ int s[256];
    int i = blockIdx.x * 256 + threadIdx.x;
    int v = (i < total) ? cnt[i] : 0;
    s[threadIdx.x] = v; __syncthreads();
    for (int o = 128; o > 0; o >>= 1) {
        if (threadIdx.x < o) s[threadIdx.x] += s[threadIdx.x + o];
        __syncthreads();
    }
    if (threadIdx.x == 0) bsum[blockIdx.x] = s[0];
}

// exclusive scan of nb block sums (nb may exceed 256): chunked Hillis-Steele + carry
__global__ void k_scanb(int* __restrict__ bsum, int nb) {
    __shared__ int s[256];
    int carry = 0;
    for (int base = 0; base < nb; base += 256) {
        int i = base + threadIdx.x;
        int v = (i < nb) ? bsum[i] : 0;
        s[threadIdx.x] = v; __syncthreads();
        for (int o = 1; o < 256; o <<= 1) {
            int t = (threadIdx.x >= o) ? s[threadIdx.x - o] : 0;
            __syncthreads();
            s[threadIdx.x] += t;
            __syncthreads();
        }
        int tot = s[255];
        if (i < nb) bsum[i] = s[threadIdx.x] - v + carry;
        carry += tot;
        __syncthreads();
    }
}

__global__ void k_rowptr8(const int* __restrict__ cnt, const int* __restrict__ bsum,
                          int* __restrict__ rp, int* __restrict__ cur, int total) {
    __shared__ int s[256];
    int i = blockIdx.x * 256 + threadIdx.x;
    int v = (i < total) ? cnt[i] : 0;
    s[threadIdx.x] = v; __syncthreads();
    for (int o = 1; o < 256; o <<= 1) {                     // Hillis-Steele inclusive
        int t = (threadIdx.x >= o) ? s[threadIdx.x - o] : 0;
        __syncthreads();
        s[threadIdx.x] += t;
        __syncthreads();
    }
    int excl = s[threadIdx.x] - v + bsum[blockIdx.x];
    if (i < total) { rp[i] = excl; cur[i] = excl; }
    if (i == total - 1) rp[total] = excl + v;
}

__global__ void k_scatter8(const int* __restrict__ src, const int* __restrict__ dst,
                           int* __restrict__ cur, int* __restrict__ col) {
    int e = blockIdx.x * 256 + threadIdx.x;
    if (e < N_EDGES) {
        int sv = src[e];
        int q = sv >> PASS_SHIFT;
        int p = atomicAdd(&cur[dst[e] * NPASS + q], 1);
        col[p] = sv;
    }
}

// -------------- weight prep: W[K][N] fp32 -> Wt[N][K] bf16 --------------
__global__ void k_wt(const float* __restrict__ w, u16* __restrict__ wt, int K, int N) {
    int idx = blockIdx.x * 256 + threadIdx.x;
    if (idx >= K * N) return;
    int n = idx / K, k = idx - n * K;
    wt[idx] = f2bf(w[(size_t)k * N + n]);
}

// -------------- x fp32 -> bf16 (halves gather bytes in agg_l1) --------------
__global__ void k_x2bf(const float* __restrict__ x, u16* __restrict__ xb) {
    int i = blockIdx.x * 256 + threadIdx.x;
    if (i < N_NODES * IN_C / 4) {
        float4 v = ((const float4*)x)[i];
        u16x4 o;
        o[0] = f2bf(v.x); o[1] = f2bf(v.y); o[2] = f2bf(v.z); o[3] = f2bf(v.w);
        ((u16x4*)xb)[i] = o;
    }
}

// ---- streaming slab gather (XCD-private lines + pass-sorted edge order) ----
// 128-B slabs: C=512 -> 8 slabs, slab=bid&7 -> each line pulled by exactly one
// XCD; C=256 -> 4 slabs, slab=bid&3 -> 2 XCDs per slab.
// One node per 16-lane group (16 nodes/block); lane owns 4 ch (8 B).
// Node's edges are contiguous & pass-sorted in col -> single streaming loop,
// 4-deep unroll = 4 independent 1-line gathers in flight (MLP restored vs r4).
// EPI 0: out bf16 = bf16(ep*self + agg).  EPI 1: out fp32 = ep*self + agg + bias.
template <int C, int EPI>
__global__ __launch_bounds__(256) void k_agg_stream(
    const u16* __restrict__ sm, const int* __restrict__ rp8,
    const int* __restrict__ col, const float* __restrict__ eps,
    const float* __restrict__ bias, void* __restrict__ out) {
    constexpr int NSLAB = C / 64;          // 128-B slabs
    const int slab  = blockIdx.x & (NSLAB - 1);
    const int chunk = blockIdx.x / NSLAB;
    const int gid = threadIdx.x >> 4;      // 16 groups of 16 lanes
    const int ln  = threadIdx.x & 15;
    const int ch0 = slab * 64 + ln * 4;
    const int n = chunk * 16 + gid;
    if (n >= N_NODES) return;
    const float ep = 1.f + eps[0];

    const int rs = rp8[n * NPASS];
    const int re = rp8[n * NPASS + NPASS];
    float a0 = 0.f, a1 = 0.f, a2 = 0.f, a3 = 0.f;
    int e = rs;
    for (; e + 4 <= re; e += 4) {
        int s0 = col[e], s1 = col[e + 1], s2 = col[e + 2], s3 = col[e + 3];
        u16x4 v0 = *(const u16x4*)(sm + (size_t)s0 * C + ch0);
        u16x4 v1 = *(const u16x4*)(sm + (size_t)s1 * C + ch0);
        u16x4 v2 = *(const u16x4*)(sm + (size_t)s2 * C + ch0);
        u16x4 v3 = *(const u16x4*)(sm + (size_t)s3 * C + ch0);
        a0 += bf2f(v0[0]) + bf2f(v1[0]) + bf2f(v2[0]) + bf2f(v3[0]);
        a1 += bf2f(v0[1]) + bf2f(v1[1]) + bf2f(v2[1]) + bf2f(v3[1]);
        a2 += bf2f(v0[2]) + bf2f(v1[2]) + bf2f(v2[2]) + bf2f(v3[2]);
        a3 += bf2f(v0[3]) + bf2f(v1[3]) + bf2f(v2[3]) + bf2f(v3[3]);
    }
    for (; e < re; e++) {
        int s0 = col[e];
        u16x4 v0 = *(const u16x4*)(sm + (size_t)s0 * C + ch0);
        a0 += bf2f(v0[0]); a1 += bf2f(v0[1]); a2 += bf2f(v0[2]); a3 += bf2f(v0[3]);
    }

    u16x4 sv = *(const u16x4*)(sm + (size_t)n * C + ch0);
    float r0 = fmaf(ep, bf2f(sv[0]), a0);
    float r1 = fmaf(ep, bf2f(sv[1]), a1);
    float r2 = fmaf(ep, bf2f(sv[2]), a2);
    float r3 = fmaf(ep, bf2f(sv[3]), a3);
    if constexpr (EPI == 0) {
        u16x4 o;
        o[0] = f2bf(r0); o[1] = f2bf(r1); o[2] = f2bf(r2); o[3] = f2bf(r3);
        *(u16x4*)((u16*)out + (size_t)n * C + ch0) = o;
    } else {
        float4 bv = *(const float4*)(bias + ch0);
        float4 o;
        o.x = r0 + bv.x; o.y = r1 + bv.y; o.z = r2 + bv.z; o.w = r3 + bv.w;
        *(float4*)((float*)out + (size_t)n * C + ch0) = o;
    }
}

// -------------- bf16 MFMA GEMM: C[M][N] = A[M][K] @ Wt[N][K]^T --------------
// 128x128 tile, BK=32, 4 waves (2x2), global_load_lds staging with both-sides
// XOR chunk swizzle (rule 21): LDS tile [128 rows][32 bf16], row=64B=4 chunks,
// chunk c' = c ^ swz4(row) gives 2-way (free) bank access on ds_read_b128.
// EPI=0: out bf16 = relu(acc + bias).  EPI=1: out bf16 = acc (no bias/relu).
template <int K, int EPI>
__global__ __launch_bounds__(256, 2) void gemm_k(
    const u16* __restrict__ A, const u16* __restrict__ Wt,
    const float* __restrict__ bias, void* __restrict__ out,
    int N, int grid_n) {
    __shared__ u16 Als[128 * 32];
    __shared__ u16 Bls[128 * 32];
    const int tid  = threadIdx.x;
    const int wave = tid >> 6, lane = tid & 63;
    const int wm = wave >> 1, wn = wave & 1;
    const int bm = blockIdx.x / grid_n, bn = blockIdx.x % grid_n;
    const int m0 = bm * 128, n0 = bn * 128;
    const int sr = lane >> 2, sc = lane & 3;       // staging: 16 rows x 4 chunks
    const int fr = lane & 15, kg = lane >> 4;      // fragment coords

    f32x4 acc[4][4];
#pragma unroll
    for (int i = 0; i < 4; i++)
#pragma unroll
        for (int j = 0; j < 4; j++) acc[i][j] = (f32x4){0.f, 0.f, 0.f, 0.f};

    for (int kk = 0; kk < K; kk += 32) {
#pragma unroll
        for (int i = 0; i < 2; i++) {
            int rl = wave * 32 + i * 16 + sr;
            int c  = sc ^ swz4(rl);                 // pre-swizzled global source
            gload16(A  + (size_t)(m0 + rl) * K + kk + c * 8,
                    &Als[(wave * 32 + i * 16) * 32]);
            gload16(Wt + (size_t)(n0 + rl) * K + kk + c * 8,
                    &Bls[(wave * 32 + i * 16) * 32]);
        }
        asm volatile("s_waitcnt vmcnt(0)" ::: "memory");
        __syncthreads();

        s16x8 af[4], bfr[4];
#pragma unroll
        for (int mi = 0; mi < 4; mi++) {
            int r = wm * 64 + mi * 16 + fr;
            int c = kg ^ swz4(r);                   // swizzled read
            af[mi] = *(const s16x8*)&Als[r * 32 + c * 8];
        }
#pragma unroll
        for (int ni = 0; ni < 4; ni++) {
            int r = wn * 64 + ni * 16 + fr;
            int c = kg ^ swz4(r);
            bfr[ni] = *(const s16x8*)&Bls[r * 32 + c * 8];
        }
#pragma unroll
        for (int mi = 0; mi < 4; mi++)
#pragma unroll
            for (int ni = 0; ni < 4; ni++)
                acc[mi][ni] = __builtin_amdgcn_mfma_f32_16x16x32_bf16(
                    af[mi], bfr[ni], acc[mi][ni], 0, 0, 0);
        __syncthreads();
    }

    // epilogue: C row = kg*4 + j, col = fr (m89/m91-verified C/D layout)
#pragma unroll
    for (int ni = 0; ni < 4; ni++) {
        int cn = n0 + wn * 64 + ni * 16 + fr;
        float bv = 0.f;
        if constexpr (EPI == 0) bv = bias[cn];
#pragma unroll
        for (int mi = 0; mi < 4; mi++) {
            int rb = m0 + wm * 64 + mi * 16 + kg * 4;
#pragma unroll
            for (int j = 0; j < 4; j++) {
                int r = rb + j;
                if (r < N_NODES) {
                    float v = acc[mi][ni][j];
                    if constexpr (EPI == 0) {
                        v += bv;
                        v = v > 0.f ? v : 0.f;
                    }
                    ((u16*)out)[(size_t)r * N + cn] = f2bf(v);
                }
            }
        }
    }
}

// ---------------- launch ----------------
extern "C" void kernel_launch(void* const* d_in, const int* in_sizes, int n_in,
                              void* d_out, int out_size, void* d_ws, size_t ws_size,
                              hipStream_t stream) {
    const float* x    = (const float*)d_in[0];
    const int*   src  = (const int*)d_in[1];
    const int*   dst  = (const int*)d_in[2];
    const float* w1   = (const float*)d_in[3];
    const float* b1   = (const float*)d_in[4];
    const float* eps1 = (const float*)d_in[5];
    const float* w2   = (const float*)d_in[6];
    const float* b2   = (const float*)d_in[7];
    const float* eps2 = (const float*)d_in[8];
    const float* w3   = (const float*)d_in[9];
    const float* b3   = (const float*)d_in[10];
    const float* eps3 = (const float*)d_in[11];

    char* ws = (char*)d_ws;
    size_t off = 0;
    auto take = [&](size_t bytes) {
        char* p = ws + off;
        off += (bytes + 255) & ~(size_t)255;
        return p;
    };
    const int TOT8 = N_NODES * NPASS;                 // 400000 buckets
    int* cnt8 = (int*)take((size_t)TOT8 * 4);
    int* rp8  = (int*)take((size_t)(TOT8 + 1) * 4);
    int* cur8 = (int*)take((size_t)TOT8 * 4);
    int* bsum = (int*)take(2048 * 4);
    int* col  = (int*)take((size_t)N_EDGES * 4);
    u16* w1t  = (u16*)take((size_t)IN_C * HID_C * 2);
    u16* w2t  = (u16*)take((size_t)HID_C * HID_C * 2);
    u16* w3t  = (u16*)take((size_t)HID_C * OUT_C * 2);
    u16* A0   = (u16*)take((size_t)M_PAD * IN_C * 2);
    u16* h1   = (u16*)take((size_t)M_PAD * HID_C * 2);
    u16* A1   = (u16*)take((size_t)M_PAD * HID_C * 2);
    // time-shared buffer: xb (phase 1) -> A1 (phase 2) -> g3 bf16 (phase 3).
    // each is fully dead before the next is written; stream order serializes.
    u16* xb = A1;            // 25.6 MB <= 51.2 MB, dead after l1 agg
    u16* h2 = h1;            // GEMM2 reads only A1 -> safe alias
    u16* g3 = A1;            // GEMM3 reads only h2 -> safe alias

    const int NB8 = (TOT8 + 255) / 256;   // 1563 scan blocks
    const int NE  = (N_EDGES + 255) / 256;

    hipMemsetAsync(cnt8, 0, (size_t)TOT8 * 4, stream);
    k_hist8  <<<NE, 256, 0, stream>>>(src, dst, cnt8);
    k_partial<<<NB8, 256, 0, stream>>>(cnt8, bsum, TOT8);
    k_scanb  <<<1, 256, 0, stream>>>(bsum, NB8);
    k_rowptr8<<<NB8, 256, 0, stream>>>(cnt8, bsum, rp8, cur8, TOT8);
    k_scatter8<<<NE, 256, 0, stream>>>(src, dst, cur8, col);

    k_wt<<<(IN_C * HID_C + 255) / 256, 256, 0, stream>>>(w1, w1t, IN_C, HID_C);
    k_wt<<<(HID_C * HID_C + 255) / 256, 256, 0, stream>>>(w2, w2t, HID_C, HID_C);
    k_wt<<<(HID_C * OUT_C + 255) / 256, 256, 0, stream>>>(w3, w3t, HID_C, OUT_C);
    k_x2bf<<<(N_NODES * IN_C / 4 + 255) / 256, 256, 0, stream>>>(x, xb);

    // grids: 16 nodes/block; C=512 -> 3125 chunks x 8 slabs; C=256 -> x 4 slabs
    const int NCH  = (N_NODES + 15) / 16;   // 3125
    const int G512 = NCH * 8;
    const int G256 = NCH * 4;

    // layer 1: aggregate (256ch bf16) then GEMM -> h1 = relu(A0 @ W1 + b1)
    k_agg_stream<IN_C, 0><<<G256, 256, 0, stream>>>(xb, rp8, col, eps1, nullptr, A0);
    gemm_k<IN_C, 0><<<391 * (HID_C / 128), 256, 0, stream>>>(
        A0, w1t, b1, h1, HID_C, HID_C / 128);

    // layer 2: aggregate (512ch) then GEMM -> h2 = relu(A1 @ W2 + b2)
    k_agg_stream<HID_C, 0><<<G512, 256, 0, stream>>>(h1, rp8, col, eps2, nullptr, A1);
    gemm_k<HID_C, 0><<<391 * (HID_C / 128), 256, 0, stream>>>(
        A1, w2t, b2, h2, HID_C, HID_C / 128);

    // layer 3: GEMM first (g3 = h2 @ W3 bf16, no bias), then aggregate + bias -> fp32
    gemm_k<HID_C, 1><<<391 * (OUT_C / 128), 256, 0, stream>>>(
        h2, w3t, nullptr, g3, OUT_C, OUT_C / 128);
    k_agg_stream<OUT_C, 1><<<G256, 256, 0, stream>>>(g3, rp8, col, eps3, b3, (float*)d_out);
}

// Round 6
// 459.093 us; speedup vs baseline: 1.6373x; 1.0424x over previous
//
#include <hip/hip_runtime.h>

#define N_NODES 50000
#define N_EDGES 800000
#define IN_C 256
#define HID_C 512
#define OUT_C 256
#define M_PAD 50048   // 391 * 128, covers 50000 with one padded tile
#define NPASS 8
#define PASS_SHIFT 13   // src >> 13 -> bucket 0..6 (8192-node source ranges)

typedef unsigned short u16;
typedef unsigned int   u32;
typedef u16  u16x4 __attribute__((ext_vector_type(4)));
typedef u16  u16x8 __attribute__((ext_vector_type(8)));
typedef short s16x8 __attribute__((ext_vector_type(8)));   // bf16 MFMA frag (guide §3)
typedef float f32x4 __attribute__((ext_vector_type(4)));

__device__ __forceinline__ float bf2f(u16 h) {
    u32 u = ((u32)h) << 16;
    return __builtin_bit_cast(float, u);
}
__device__ __forceinline__ u16 f2bf(float f) {   // round-to-nearest-even
    u32 u = __builtin_bit_cast(u32, f);
    u32 r = u + 0x7fffu + ((u >> 16) & 1u);
    return (u16)(r >> 16);
}
__device__ __forceinline__ void gload16(const void* g, void* l) {
    __builtin_amdgcn_global_load_lds(
        (const __attribute__((address_space(1))) u32*)g,
        (__attribute__((address_space(3))) u32*)l, 16, 0, 0);
}

// ---------------- sub-CSR build: buckets (dst, src>>13) ----------------
// col ends up sorted by (dst, src>>13): per node the edge list is contiguous
// [rp8[n*8], rp8[n*8+8]) AND pass-sorted (source-window-ascending).
__global__ void k_hist8(const int* __restrict__ src, const int* __restrict__ dst,
                        int* __restrict__ cnt8) {
    int e = blockIdx.x * 256 + threadIdx.x;
    if (e < N_EDGES) {
        int q = src[e] >> PASS_SHIFT;
        atomicAdd(&cnt8[dst[e] * NPASS + q], 1);
    }
}

__global__ void k_partial(const int* __restrict__ cnt, int* __restrict__ bsum, int total) {
    __shared__ int s[256];
    int i = blockIdx.x * 256 + threadIdx.x;
    int v = (i < total) ? cnt[i] : 0;
    s[threadIdx.x] = v; __syncthreads();
    for (int o = 128; o > 0; o >>= 1) {
        if (threadIdx.x < o) s[threadIdx.x] += s[threadIdx.x + o];
        __syncthreads();
    }
    if (threadIdx.x == 0) bsum[blockIdx.x] = s[0];
}

// exclusive scan of nb block sums (nb may exceed 256): chunked Hillis-Steele + carry
__global__ void k_scanb(int* __restrict__ bsum, int nb) {
    __shared__ int s[256];
    int carry = 0;
    for (int base = 0; base < nb; base += 256) {
        int i = base + threadIdx.x;
        int v = (i < nb) ? bsum[i] : 0;
        s[threadIdx.x] = v; __syncthreads();
        for (int o = 1; o < 256; o <<= 1) {
            int t = (threadIdx.x >= o) ? s[threadIdx.x - o] : 0;
            __syncthreads();
            s[threadIdx.x] += t;
            __syncthreads();
        }
        int tot = s[255];
        if (i < nb) bsum[i] = s[threadIdx.x] - v + carry;
        carry += tot;
        __syncthreads();
    }
}

__global__ void k_rowptr8(const int* __restrict__ cnt, const int* __restrict__ bsum,
                          int* __restrict__ rp, int* __restrict__ cur, int total) {
    __shared__ int s[256];
    int i = blockIdx.x * 256 + threadIdx.x;
    int v = (i < total) ? cnt[i] : 0;
    s[threadIdx.x] = v; __syncthreads();
    for (int o = 1; o < 256; o <<= 1) {                     // Hillis-Steele inclusive
        int t = (threadIdx.x >= o) ? s[threadIdx.x - o] : 0;
        __syncthreads();
        s[threadIdx.x] += t;
        __syncthreads();
    }
    int excl = s[threadIdx.x] - v + bsum[blockIdx.x];
    if (i < total) { rp[i] = excl; cur[i] = excl; }
    if (i == total - 1) rp[total] = excl + v;
}

__global__ void k_scatter8(const int* __restrict__ src, const int* __restrict__ dst,
                           int* __restrict__ cur, int* __restrict__ col) {
    int e = blockIdx.x * 256 + threadIdx.x;
    if (e < N_EDGES) {
        int sv = src[e];
        int q = sv >> PASS_SHIFT;
        int p = atomicAdd(&cur[dst[e] * NPASS + q], 1);
        col[p] = sv;
    }
}

// -------------- weight prep: W[K][N] fp32 -> Wt[N][K] bf16 --------------
__global__ void k_wt(const float* __restrict__ w, u16* __restrict__ wt, int K, int N) {
    int idx = blockIdx.x * 256 + threadIdx.x;
    if (idx >= K * N) return;
    int n = idx / K, k = idx - n * K;
    wt[idx] = f2bf(w[(size_t)k * N + n]);
}

// -------------- x fp32 -> bf16 (halves gather bytes in agg_l1) --------------
__global__ void k_x2bf(const float* __restrict__ x, u16* __restrict__ xb) {
    int i = blockIdx.x * 256 + threadIdx.x;
    if (i < N_NODES * IN_C / 4) {
        float4 v = ((const float4*)x)[i];
        u16x4 o;
        o[0] = f2bf(v.x); o[1] = f2bf(v.y); o[2] = f2bf(v.z); o[3] = f2bf(v.w);
        ((u16x4*)xb)[i] = o;
    }
}

// ---- streaming slab gather (XCD-private lines + pass-sorted edge order) ----
// 128-B slabs: C=512 -> 8 slabs, slab=bid&7 -> each line pulled by exactly one
// XCD; C=256 -> 4 slabs, slab=bid&3 -> 2 XCDs per slab.
// One node per 16-lane group (16 nodes/block); lane owns 4 ch (8 B).
// Node's edges are contiguous & pass-sorted in col -> single streaming loop,
// 4-deep unroll = 4 independent 1-line gathers in flight.
// EPI 0: out bf16 = bf16(ep*self + agg).  EPI 1: out fp32 = ep*self + agg + bias.
template <int C, int EPI>
__global__ __launch_bounds__(256) void k_agg_stream(
    const u16* __restrict__ sm, const int* __restrict__ rp8,
    const int* __restrict__ col, const float* __restrict__ eps,
    const float* __restrict__ bias, void* __restrict__ out) {
    constexpr int NSLAB = C / 64;          // 128-B slabs
    const int slab  = blockIdx.x & (NSLAB - 1);
    const int chunk = blockIdx.x / NSLAB;
    const int gid = threadIdx.x >> 4;      // 16 groups of 16 lanes
    const int ln  = threadIdx.x & 15;
    const int ch0 = slab * 64 + ln * 4;
    const int n = chunk * 16 + gid;
    if (n >= N_NODES) return;
    const float ep = 1.f + eps[0];

    const int rs = rp8[n * NPASS];
    const int re = rp8[n * NPASS + NPASS];
    float a0 = 0.f, a1 = 0.f, a2 = 0.f, a3 = 0.f;
    int e = rs;
    for (; e + 4 <= re; e += 4) {
        int s0 = col[e], s1 = col[e + 1], s2 = col[e + 2], s3 = col[e + 3];
        u16x4 v0 = *(const u16x4*)(sm + (size_t)s0 * C + ch0);
        u16x4 v1 = *(const u16x4*)(sm + (size_t)s1 * C + ch0);
        u16x4 v2 = *(const u16x4*)(sm + (size_t)s2 * C + ch0);
        u16x4 v3 = *(const u16x4*)(sm + (size_t)s3 * C + ch0);
        a0 += bf2f(v0[0]) + bf2f(v1[0]) + bf2f(v2[0]) + bf2f(v3[0]);
        a1 += bf2f(v0[1]) + bf2f(v1[1]) + bf2f(v2[1]) + bf2f(v3[1]);
        a2 += bf2f(v0[2]) + bf2f(v1[2]) + bf2f(v2[2]) + bf2f(v3[2]);
        a3 += bf2f(v0[3]) + bf2f(v1[3]) + bf2f(v2[3]) + bf2f(v3[3]);
    }
    for (; e < re; e++) {
        int s0 = col[e];
        u16x4 v0 = *(const u16x4*)(sm + (size_t)s0 * C + ch0);
        a0 += bf2f(v0[0]); a1 += bf2f(v0[1]); a2 += bf2f(v0[2]); a3 += bf2f(v0[3]);
    }

    u16x4 sv = *(const u16x4*)(sm + (size_t)n * C + ch0);
    float r0 = fmaf(ep, bf2f(sv[0]), a0);
    float r1 = fmaf(ep, bf2f(sv[1]), a1);
    float r2 = fmaf(ep, bf2f(sv[2]), a2);
    float r3 = fmaf(ep, bf2f(sv[3]), a3);
    if constexpr (EPI == 0) {
        u16x4 o;
        o[0] = f2bf(r0); o[1] = f2bf(r1); o[2] = f2bf(r2); o[3] = f2bf(r3);
        *(u16x4*)((u16*)out + (size_t)n * C + ch0) = o;
    } else {
        float4 bv = *(const float4*)(bias + ch0);
        float4 o;
        o.x = r0 + bv.x; o.y = r1 + bv.y; o.z = r2 + bv.z; o.w = r3 + bv.w;
        *(float4*)((float*)out + (size_t)n * C + ch0) = o;
    }
}

// -------------- bf16 MFMA GEMM: C[M][N] = A[M][K] @ Wt[N][K]^T --------------
// 128x128 tile, BK=64 (32 MFMA per vmcnt/barrier drain), 4 waves (2x2).
// Staging: global_load_lds w16, linear LDS dest, chunk-XOR swizzle c^=(r&7)
// applied on BOTH global source and ds_read (rule 21) -> 2-way (free) banks.
// Epilogue: acc -> bf16 -> LDS C-tile [128][130] (pad => bank=(r+4k)&31,
// conflict-free b128 readback), then coalesced u16x8 global stores
// (128 contiguous B per thread, full 256-B row segments per lane pair).
// EPI=0: out bf16 = relu(acc + bias).  EPI=1: out bf16 = acc.
template <int K, int EPI>
__global__ __launch_bounds__(256, 2) void gemm_k(
    const u16* __restrict__ A, const u16* __restrict__ Wt,
    const float* __restrict__ bias, void* __restrict__ out,
    int N, int grid_n) {
    __shared__ u16 smem[16640];            // max(Als+Bls = 16384, Cls = 16640)
    u16* Als = smem;                       // [128][64]
    u16* Bls = smem + 8192;                // [128][64]
    const int tid  = threadIdx.x;
    const int wave = tid >> 6, lane = tid & 63;
    const int wm = wave >> 1, wn = wave & 1;
    const int bm = blockIdx.x / grid_n, bn = blockIdx.x % grid_n;
    const int m0 = bm * 128, n0 = bn * 128;
    const int sr = lane >> 3, sc = lane & 7;       // staging: 8 rows x 8 chunks
    const int fr = lane & 15, kg = lane >> 4;      // fragment coords

    f32x4 acc[4][4];
#pragma unroll
    for (int i = 0; i < 4; i++)
#pragma unroll
        for (int j = 0; j < 4; j++) acc[i][j] = (f32x4){0.f, 0.f, 0.f, 0.f};

    for (int kk = 0; kk < K; kk += 64) {
#pragma unroll
        for (int i = 0; i < 4; i++) {
            int rl = wave * 32 + i * 8 + sr;
            int cs = sc ^ (rl & 7);                 // pre-swizzled global source
            gload16(A  + (size_t)(m0 + rl) * K + kk + cs * 8,
                    &Als[(wave * 32 + i * 8) * 64]);
            gload16(Wt + (size_t)(n0 + rl) * K + kk + cs * 8,
                    &Bls[(wave * 32 + i * 8) * 64]);
        }
        asm volatile("s_waitcnt vmcnt(0)" ::: "memory");
        __syncthreads();

#pragma unroll
        for (int k2 = 0; k2 < 2; k2++) {
            s16x8 af[4], bfr[4];
#pragma unroll
            for (int mi = 0; mi < 4; mi++) {
                int r = wm * 64 + mi * 16 + fr;
                int c = (k2 * 4 + kg) ^ (r & 7);    // swizzled read
                af[mi] = *(const s16x8*)&Als[r * 64 + c * 8];
            }
#pragma unroll
            for (int ni = 0; ni < 4; ni++) {
                int r = wn * 64 + ni * 16 + fr;
                int c = (k2 * 4 + kg) ^ (r & 7);
                bfr[ni] = *(const s16x8*)&Bls[r * 64 + c * 8];
            }
#pragma unroll
            for (int mi = 0; mi < 4; mi++)
#pragma unroll
                for (int ni = 0; ni < 4; ni++)
                    acc[mi][ni] = __builtin_amdgcn_mfma_f32_16x16x32_bf16(
                        af[mi], bfr[ni], acc[mi][ni], 0, 0, 0);
        }
        __syncthreads();
    }

    // epilogue: C row = kg*4 + j, col = fr (m89/m91-verified C/D layout)
    // bounce through LDS [128][130] for coalesced output
    u16* Cls = smem;
#pragma unroll
    for (int ni = 0; ni < 4; ni++) {
        int c = wn * 64 + ni * 16 + fr;
        float bv = 0.f;
        if constexpr (EPI == 0) bv = bias[n0 + c];
#pragma unroll
        for (int mi = 0; mi < 4; mi++) {
#pragma unroll
            for (int j = 0; j < 4; j++) {
                int r = wm * 64 + mi * 16 + kg * 4 + j;
                float v = acc[mi][ni][j];
                if constexpr (EPI == 0) {
                    v += bv;
                    v = v > 0.f ? v : 0.f;
                }
                Cls[r * 130 + c] = f2bf(v);
            }
        }
    }
    __syncthreads();

    const int r2 = tid >> 1;                  // 0..127
    const int cb = (tid & 1) * 64;            // two 64-col halves
    if (m0 + r2 < N_NODES) {
        u16* orow = (u16*)out + (size_t)(m0 + r2) * N + n0 + cb;
#pragma unroll
        for (int k = 0; k < 8; k++) {
            u16x8 val = *(const u16x8*)&Cls[r2 * 130 + cb + k * 8];
            *(u16x8*)(orow + k * 8) = val;
        }
    }
}

// ---------------- launch ----------------
extern "C" void kernel_launch(void* const* d_in, const int* in_sizes, int n_in,
                              void* d_out, int out_size, void* d_ws, size_t ws_size,
                              hipStream_t stream) {
    const float* x    = (const float*)d_in[0];
    const int*   src  = (const int*)d_in[1];
    const int*   dst  = (const int*)d_in[2];
    const float* w1   = (const float*)d_in[3];
    const float* b1   = (const float*)d_in[4];
    const float* eps1 = (const float*)d_in[5];
    const float* w2   = (const float*)d_in[6];
    const float* b2   = (const float*)d_in[7];
    const float* eps2 = (const float*)d_in[8];
    const float* w3   = (const float*)d_in[9];
    const float* b3   = (const float*)d_in[10];
    const float* eps3 = (const float*)d_in[11];

    char* ws = (char*)d_ws;
    size_t off = 0;
    auto take = [&](size_t bytes) {
        char* p = ws + off;
        off += (bytes + 255) & ~(size_t)255;
        return p;
    };
    const int TOT8 = N_NODES * NPASS;                 // 400000 buckets
    int* cnt8 = (int*)take((size_t)TOT8 * 4);
    int* rp8  = (int*)take((size_t)(TOT8 + 1) * 4);
    int* cur8 = (int*)take((size_t)TOT8 * 4);
    int* bsum = (int*)take(2048 * 4);
    int* col  = (int*)take((size_t)N_EDGES * 4);
    u16* w1t  = (u16*)take((size_t)IN_C * HID_C * 2);
    u16* w2t  = (u16*)take((size_t)HID_C * HID_C * 2);
    u16* w3t  = (u16*)take((size_t)HID_C * OUT_C * 2);
    u16* A0   = (u16*)take((size_t)M_PAD * IN_C * 2);
    u16* h1   = (u16*)take((size_t)M_PAD * HID_C * 2);
    u16* A1   = (u16*)take((size_t)M_PAD * HID_C * 2);
    // time-shared buffer: xb (phase 1) -> A1 (phase 2) -> g3 bf16 (phase 3).
    // each is fully dead before the next is written; stream order serializes.
    u16* xb = A1;            // 25.6 MB <= 51.2 MB, dead after l1 agg
    u16* h2 = h1;            // GEMM2 reads only A1 -> safe alias
    u16* g3 = A1;            // GEMM3 reads only h2 -> safe alias

    const int NB8 = (TOT8 + 255) / 256;   // 1563 scan blocks
    const int NE  = (N_EDGES + 255) / 256;

    hipMemsetAsync(cnt8, 0, (size_t)TOT8 * 4, stream);
    k_hist8  <<<NE, 256, 0, stream>>>(src, dst, cnt8);
    k_partial<<<NB8, 256, 0, stream>>>(cnt8, bsum, TOT8);
    k_scanb  <<<1, 256, 0, stream>>>(bsum, NB8);
    k_rowptr8<<<NB8, 256, 0, stream>>>(cnt8, bsum, rp8, cur8, TOT8);
    k_scatter8<<<NE, 256, 0, stream>>>(src, dst, cur8, col);

    k_wt<<<(IN_C * HID_C + 255) / 256, 256, 0, stream>>>(w1, w1t, IN_C, HID_C);
    k_wt<<<(HID_C * HID_C + 255) / 256, 256, 0, stream>>>(w2, w2t, HID_C, HID_C);
    k_wt<<<(HID_C * OUT_C + 255) / 256, 256, 0, stream>>>(w3, w3t, HID_C, OUT_C);
    k_x2bf<<<(N_NODES * IN_C / 4 + 255) / 256, 256, 0, stream>>>(x, xb);

    // grids: 16 nodes/block; C=512 -> 3125 chunks x 8 slabs; C=256 -> x 4 slabs
    const int NCH  = (N_NODES + 15) / 16;   // 3125
    const int G512 = NCH * 8;
    const int G256 = NCH * 4;

    // layer 1: aggregate (256ch bf16) then GEMM -> h1 = relu(A0 @ W1 + b1)
    k_agg_stream<IN_C, 0><<<G256, 256, 0, stream>>>(xb, rp8, col, eps1, nullptr, A0);
    gemm_k<IN_C, 0><<<391 * (HID_C / 128), 256, 0, stream>>>(
        A0, w1t, b1, h1, HID_C, HID_C / 128);

    // layer 2: aggregate (512ch) then GEMM -> h2 = relu(A1 @ W2 + b2)
    k_agg_stream<HID_C, 0><<<G512, 256, 0, stream>>>(h1, rp8, col, eps2, nullptr, A1);
    gemm_k<HID_C, 0><<<391 * (HID_C / 128), 256, 0, stream>>>(
        A1, w2t, b2, h2, HID_C, HID_C / 128);

    // layer 3: GEMM first (g3 = h2 @ W3 bf16, no bias), then aggregate + bias -> fp32
    gemm_k<HID_C, 1><<<391 * (OUT_C / 128), 256, 0, stream>>>(
        h2, w3t, nullptr, g3, OUT_C, OUT_C / 128);
    k_agg_stream<OUT_C, 1><<<G256, 256, 0, stream>>>(g3, rp8, col, eps3, b3, (float*)d_out);
}